// Round 1
// baseline (396.830 us; speedup 1.0000x reference)
//
#include <hip/hip_runtime.h>
#include <math.h>

#define B_ 64
#define N_ 16384
#define M_ 64

// ---------------- Pass A: scores s[b,n] = beta_b * cos(key_b, memory[b,n,:]) ----------------
// grid = (N/256, B), block = 256 (4 waves). Each wave: 4 rows per iter, 16 lanes per row,
// each lane loads float4 -> one wave load = 64 lanes * 16B = 1KB fully contiguous.
__global__ __launch_bounds__(256) void scores_kernel(
    const float* __restrict__ key, const float* __restrict__ beta,
    const float* __restrict__ memory, float* __restrict__ s_out)
{
    const int b    = blockIdx.y;
    const int tid  = threadIdx.x;
    const int lane = tid & 63;
    const int wave = tid >> 6;    // 0..3
    const int l    = lane & 15;   // element group within row
    const int g    = lane >> 4;   // row within quad

    const float4 k4 = *reinterpret_cast<const float4*>(key + b * M_ + l * 4);
    float ksq = k4.x * k4.x + k4.y * k4.y + k4.z * k4.z + k4.w * k4.w;
#pragma unroll
    for (int m = 1; m < 16; m <<= 1) ksq += __shfl_xor(ksq, m);
    const float knorm = sqrtf(ksq);
    const float kb    = beta[b];

    const float* __restrict__ mb = memory + (size_t)b * N_ * M_;
    float* __restrict__ sb       = s_out + (size_t)b * N_;

    const int rowBase = blockIdx.x * 256 + wave * 64;
#pragma unroll 4
    for (int i = 0; i < 16; ++i) {
        const int r = rowBase + i * 4 + g;
        const float4 m4 = *reinterpret_cast<const float4*>(mb + (size_t)r * M_ + l * 4);
        float dot = k4.x * m4.x + k4.y * m4.y + k4.z * m4.z + k4.w * m4.w;
        float msq = m4.x * m4.x + m4.y * m4.y + m4.z * m4.z + m4.w * m4.w;
#pragma unroll
        for (int m = 1; m < 16; m <<= 1) {
            dot += __shfl_xor(dot, m);
            msq += __shfl_xor(msq, m);
        }
        if (l == 0) {
            const float denom = fmaxf(knorm * sqrtf(msq), 1e-8f);
            sb[r] = kb * dot / denom;
        }
    }
}

// ---------------- Pass B: softmax + gate + circular shift + sharpen + renorm ----------------
// One block (1024 threads) per batch. Each thread owns 16 contiguous elements in registers.
__global__ __launch_bounds__(1024) void addr_kernel(
    const float* __restrict__ gate, const float* __restrict__ shift,
    const float* __restrict__ sharpen, const float* __restrict__ la,
    float* __restrict__ out)
{
    const int b    = blockIdx.x;
    const int t    = threadIdx.x;   // 0..1023
    const int lane = t & 63;
    const int wv   = t >> 6;        // 0..15

    __shared__ float red[16];
    __shared__ float lft[1024];
    __shared__ float rgt[1024];

    float* __restrict__ ob        = out + (size_t)b * N_;
    const float* __restrict__ lab = la + (size_t)b * N_;

    // load scores (this batch's slice of d_out) into registers
    float s[16];
#pragma unroll
    for (int q = 0; q < 4; ++q)
        *reinterpret_cast<float4*>(&s[4 * q]) =
            reinterpret_cast<const float4*>(ob)[t * 4 + q];

    // ---- block max ----
    float mx = s[0];
#pragma unroll
    for (int i = 1; i < 16; ++i) mx = fmaxf(mx, s[i]);
#pragma unroll
    for (int m = 1; m < 64; m <<= 1) mx = fmaxf(mx, __shfl_xor(mx, m));
    if (lane == 0) red[wv] = mx;
    __syncthreads();
    mx = red[0];
#pragma unroll
    for (int i = 1; i < 16; ++i) mx = fmaxf(mx, red[i]);
    __syncthreads();

    // ---- exp + block sum ----
    float zs = 0.f;
#pragma unroll
    for (int i = 0; i < 16; ++i) { s[i] = expf(s[i] - mx); zs += s[i]; }
#pragma unroll
    for (int m = 1; m < 64; m <<= 1) zs += __shfl_xor(zs, m);
    if (lane == 0) red[wv] = zs;
    __syncthreads();
    float Z = red[0];
#pragma unroll
    for (int i = 1; i < 16; ++i) Z += red[i];
    __syncthreads();
    const float invZ = 1.0f / Z;

    // ---- gate interpolation ----
    const float gg = gate[b];
    const float om = 1.0f - gg;
    float wl[16];
#pragma unroll
    for (int q = 0; q < 4; ++q)
        *reinterpret_cast<float4*>(&wl[4 * q]) =
            reinterpret_cast<const float4*>(lab)[t * 4 + q];
    float wg[16];
#pragma unroll
    for (int i = 0; i < 16; ++i) wg[i] = gg * (s[i] * invZ) + om * wl[i];

    // ---- circular 3-tap shift: boundary exchange via LDS ----
    lft[t] = wg[0];
    rgt[t] = wg[15];
    __syncthreads();
    const float prev = rgt[(t + 1023) & 1023];
    const float nxt  = lft[(t + 1) & 1023];
    const float s0 = shift[b * 3 + 0];
    const float s1 = shift[b * 3 + 1];
    const float s2 = shift[b * 3 + 2];
    float ws[16];
    ws[0] = s0 * prev + s1 * wg[0] + s2 * wg[1];
#pragma unroll
    for (int i = 1; i < 15; ++i) ws[i] = s0 * wg[i - 1] + s1 * wg[i] + s2 * wg[i + 1];
    ws[15] = s0 * wg[14] + s1 * wg[15] + s2 * nxt;

    // ---- sharpen + block sum + renorm ----
    const float p = sharpen[b];
    float ssum = 0.f;
#pragma unroll
    for (int i = 0; i < 16; ++i) { ws[i] = powf(ws[i], p); ssum += ws[i]; }
#pragma unroll
    for (int m = 1; m < 64; m <<= 1) ssum += __shfl_xor(ssum, m);
    __syncthreads();   // red reuse: ensure previous reads done
    if (lane == 0) red[wv] = ssum;
    __syncthreads();
    float S = red[0];
#pragma unroll
    for (int i = 1; i < 16; ++i) S += red[i];
    const float inv = 1.0f / (S + 1e-16f);

#pragma unroll
    for (int q = 0; q < 4; ++q) {
        float4 o;
        o.x = ws[4 * q + 0] * inv;
        o.y = ws[4 * q + 1] * inv;
        o.z = ws[4 * q + 2] * inv;
        o.w = ws[4 * q + 3] * inv;
        reinterpret_cast<float4*>(ob)[t * 4 + q] = o;
    }
}

extern "C" void kernel_launch(void* const* d_in, const int* in_sizes, int n_in,
                              void* d_out, int out_size, void* d_ws, size_t ws_size,
                              hipStream_t stream) {
    const float* key     = (const float*)d_in[0];  // [B, M]
    const float* beta    = (const float*)d_in[1];  // [B, 1]
    const float* gate    = (const float*)d_in[2];  // [B, 1]
    const float* shift   = (const float*)d_in[3];  // [B, 3]
    const float* sharpen = (const float*)d_in[4];  // [B, 1]
    const float* la      = (const float*)d_in[5];  // [B, N]
    const float* memory  = (const float*)d_in[6];  // [B, N, M]
    float* out = (float*)d_out;                    // [B, N] (also used as score scratch)

    dim3 gridA(N_ / 256, B_);
    scores_kernel<<<gridA, 256, 0, stream>>>(key, beta, memory, out);

    addr_kernel<<<B_, 1024, 0, stream>>>(gate, shift, sharpen, la, out);
}

// Round 3
// 357.418 us; speedup vs baseline: 1.1103x; 1.1103x over previous
//
#include <hip/hip_runtime.h>
#include <math.h>

#define B_ 64
#define N_ 16384
#define M_ 64

// Native clang vector type — required by __builtin_nontemporal_load
// (HIP's float4 is a class and is rejected). Same 16B layout/alignment.
typedef float vfloat4 __attribute__((ext_vector_type(4)));

// ---------------- Pass A: s[b,n] = exp(beta_b * cos(key_b, memory[b,n,:])) ----------------
// grid = (N/256, B), block = 256 (4 waves). Layout: 4 lanes per row, each lane loads
// 4x float4 (one 64B row-quarter per load instr -> every 64B segment fully covered).
// Cross-lane reduction is quad-local: __shfl_xor(1/2) -> DPP quad_perm, zero DS-pipe.
// Since |beta*cos| <= 5, exp() is overflow-safe without max subtraction -> fold it here.
__global__ __launch_bounds__(256) void scores_kernel(
    const float* __restrict__ key, const float* __restrict__ beta,
    const float* __restrict__ memory, float* __restrict__ s_out)
{
    const int b    = blockIdx.y;
    const int tid  = threadIdx.x;
    const int lane = tid & 63;
    const int wave = tid >> 6;    // 0..3
    const int l    = lane & 3;    // 16B chunk within a 64B row-quarter
    const int rr   = lane >> 2;   // row within group of 16

    // per-lane key fragments: k4[j] = key[b, j*16 + l*4 .. +4]
    vfloat4 k4[4];
#pragma unroll
    for (int j = 0; j < 4; ++j)
        k4[j] = *reinterpret_cast<const vfloat4*>(key + b * M_ + j * 16 + l * 4);

    float ksq = 0.f;
#pragma unroll
    for (int j = 0; j < 4; ++j)
        ksq += k4[j].x * k4[j].x + k4[j].y * k4[j].y + k4[j].z * k4[j].z + k4[j].w * k4[j].w;
    ksq += __shfl_xor(ksq, 1);   // DPP quad_perm
    ksq += __shfl_xor(ksq, 2);
    const float knorm = sqrtf(ksq);
    const float kb    = beta[b];

    const float* __restrict__ mb = memory + (size_t)b * N_ * M_;
    float* __restrict__ sb       = s_out + (size_t)b * N_;

    const int rowBase = blockIdx.x * 256 + wave * 64;   // this wave owns 64 rows
#pragma unroll
    for (int t = 0; t < 4; ++t) {                       // 16 rows (4 KB) per iter
        const int row = rowBase + t * 16 + rr;
        const float* rp = mb + (size_t)row * M_;
        vfloat4 m4[4];
#pragma unroll
        for (int j = 0; j < 4; ++j)
            m4[j] = __builtin_nontemporal_load(
                reinterpret_cast<const vfloat4*>(rp + j * 16 + l * 4));

        float dot = 0.f, msq = 0.f;
#pragma unroll
        for (int j = 0; j < 4; ++j) {
            dot += k4[j].x * m4[j].x + k4[j].y * m4[j].y + k4[j].z * m4[j].z + k4[j].w * m4[j].w;
            msq += m4[j].x * m4[j].x + m4[j].y * m4[j].y + m4[j].z * m4[j].z + m4[j].w * m4[j].w;
        }
        dot += __shfl_xor(dot, 1);  dot += __shfl_xor(dot, 2);   // DPP quad reduce
        msq += __shfl_xor(msq, 1);  msq += __shfl_xor(msq, 2);

        if (l == 0) {
            const float denom = fmaxf(knorm * sqrtf(msq), 1e-8f);
            sb[row] = expf(kb * dot / denom);   // 16 consecutive floats per wave-iter
        }
    }
}

// ---------------- Pass B: softmax-denominator + gate + circular shift + sharpen + renorm ----
// One block (1024 threads) per batch; each thread owns 16 contiguous elements in registers.
// Scores arrive already exponentiated -> only a sum reduction is needed for softmax.
__global__ __launch_bounds__(1024) void addr_kernel(
    const float* __restrict__ gate, const float* __restrict__ shift,
    const float* __restrict__ sharpen, const float* __restrict__ la,
    float* __restrict__ out)
{
    const int b    = blockIdx.x;
    const int t    = threadIdx.x;   // 0..1023
    const int lane = t & 63;
    const int wv   = t >> 6;        // 0..15

    __shared__ float red[16];
    __shared__ float lft[1024];
    __shared__ float rgt[1024];

    float* __restrict__ ob        = out + (size_t)b * N_;
    const float* __restrict__ lab = la + (size_t)b * N_;

    // load exp-scores (this batch's slice of d_out) into registers
    float s[16];
#pragma unroll
    for (int q = 0; q < 4; ++q)
        *reinterpret_cast<float4*>(&s[4 * q]) =
            reinterpret_cast<const float4*>(ob)[t * 4 + q];

    // ---- block sum -> softmax denominator ----
    float zs = 0.f;
#pragma unroll
    for (int i = 0; i < 16; ++i) zs += s[i];
#pragma unroll
    for (int m = 1; m < 64; m <<= 1) zs += __shfl_xor(zs, m);
    if (lane == 0) red[wv] = zs;
    __syncthreads();
    float Z = red[0];
#pragma unroll
    for (int i = 1; i < 16; ++i) Z += red[i];
    __syncthreads();
    const float invZ = 1.0f / Z;

    // ---- gate interpolation ----
    const float gg = gate[b];
    const float om = 1.0f - gg;
    float wl[16];
#pragma unroll
    for (int q = 0; q < 4; ++q)
        *reinterpret_cast<float4*>(&wl[4 * q]) =
            reinterpret_cast<const float4*>(lab)[t * 4 + q];
    float wg[16];
#pragma unroll
    for (int i = 0; i < 16; ++i) wg[i] = gg * (s[i] * invZ) + om * wl[i];

    // ---- circular 3-tap shift: boundary exchange via LDS ----
    lft[t] = wg[0];
    rgt[t] = wg[15];
    __syncthreads();
    const float prev = rgt[(t + 1023) & 1023];
    const float nxt  = lft[(t + 1) & 1023];
    const float s0 = shift[b * 3 + 0];
    const float s1 = shift[b * 3 + 1];
    const float s2 = shift[b * 3 + 2];
    float ws[16];
    ws[0] = s0 * prev + s1 * wg[0] + s2 * wg[1];
#pragma unroll
    for (int i = 1; i < 15; ++i) ws[i] = s0 * wg[i - 1] + s1 * wg[i] + s2 * wg[i + 1];
    ws[15] = s0 * wg[14] + s1 * wg[15] + s2 * nxt;

    // ---- sharpen (x^p = exp2(p*log2 x), valid for x>=0) + block sum + renorm ----
    const float p = sharpen[b];
    float ssum = 0.f;
#pragma unroll
    for (int i = 0; i < 16; ++i) { ws[i] = exp2f(p * log2f(ws[i])); ssum += ws[i]; }
#pragma unroll
    for (int m = 1; m < 64; m <<= 1) ssum += __shfl_xor(ssum, m);
    __syncthreads();   // red reuse: ensure previous reads done
    if (lane == 0) red[wv] = ssum;
    __syncthreads();
    float S = red[0];
#pragma unroll
    for (int i = 1; i < 16; ++i) S += red[i];
    const float inv = 1.0f / (S + 1e-16f);

#pragma unroll
    for (int q = 0; q < 4; ++q) {
        float4 o;
        o.x = ws[4 * q + 0] * inv;
        o.y = ws[4 * q + 1] * inv;
        o.z = ws[4 * q + 2] * inv;
        o.w = ws[4 * q + 3] * inv;
        reinterpret_cast<float4*>(ob)[t * 4 + q] = o;
    }
}

extern "C" void kernel_launch(void* const* d_in, const int* in_sizes, int n_in,
                              void* d_out, int out_size, void* d_ws, size_t ws_size,
                              hipStream_t stream) {
    const float* key     = (const float*)d_in[0];  // [B, M]
    const float* beta    = (const float*)d_in[1];  // [B, 1]
    const float* gate    = (const float*)d_in[2];  // [B, 1]
    const float* shift   = (const float*)d_in[3];  // [B, 3]
    const float* sharpen = (const float*)d_in[4];  // [B, 1]
    const float* la      = (const float*)d_in[5];  // [B, N]
    const float* memory  = (const float*)d_in[6];  // [B, N, M]
    float* out = (float*)d_out;                    // [B, N] (also used as exp-score scratch)

    dim3 gridA(N_ / 256, B_);
    scores_kernel<<<gridA, 256, 0, stream>>>(key, beta, memory, out);

    addr_kernel<<<B_, 1024, 0, stream>>>(gate, shift, sharpen, la, out);
}